// Round 13
// baseline (65.040 us; speedup 1.0000x reference)
//
#include <hip/hip_runtime.h>

#define BATCH 8
#define ROWS 1536
#define KCLS 32
#define NTOT (BATCH*ROWS)        // 12288
#define ELEMS (NTOT*16)          // 196608
#define SSTRIDE 3073             // padded prefix-sum stride per batch
#define BIGF 1.0e30f

// workspace layout (float offsets)
enum : int {
  WS_Z     = 0,                          // [8][1536][16]
  WS_XS    = WS_Z + NTOT*16,             // [8][1536]
  WS_S     = WS_XS + NTOT,               // [8][3073] padded
  WS_DESC  = WS_S + BATCH*SSTRIDE,       // [8][1536] int
  WS_ASCP  = WS_DESC + NTOT,             // [4][12288] int
  WS_DSCP  = WS_ASCP + 4*NTOT,           // [4][12288] int
  WS_GPART = WS_DSCP + 4*NTOT,           // max([8][96][512] cpart, [8][8][1536] k8a)
  WS_LOSSP = WS_GPART + BATCH*96*512,    // [768]
  WS_D2    = WS_LOSSP + 768,             // [8][1536]
  WS_MM    = WS_D2 + NTOT,               // [48][2]
};
#define WS_CPART WS_GPART   // disjoint lifetimes: cpart k1->kmid, gpart k8a->k8b

// LDS weight layout (float offsets)
#define LW1  0
#define LB1  512
#define LW2  544
#define LB2  2592
#define LMW  2656
#define LMB  3680
#define LDW1 3696
#define LDB1 4208
#define LDW2 4240
#define LDB2 4752
#define LTOT 4768

// activation features per row (float offsets, all multiples of 4)
#define AX   0
#define AH1  16
#define AH2  48
#define AZ   112
#define AR1  128
#define AREC 144
#define ASTRIDE 164   // row stride in floats; 164%32=4 -> 2-way max conflicts

#define RPB 16        // rows per block in k1

// One layer slice: thread (lrow, fway) computes outputs [fway*OUT_PW, ..+OUT_PW)
template<int IN_BASE, int IN_N, int OUT_BASE, int OUT_PW, int OUT_TOT,
         int WOFF, int BOFF, bool RELU>
__device__ __forceinline__ void layerw(float* __restrict__ act,
                                       const float* __restrict__ wsh,
                                       int lrow, int fway)
{
  const int o0 = fway * OUT_PW;
  float acc[OUT_PW];
#pragma unroll
  for (int j = 0; j < OUT_PW; ++j) acc[j] = wsh[BOFF + o0 + j];

  const float4* arow = reinterpret_cast<const float4*>(&act[lrow*ASTRIDE + IN_BASE]);
#pragma unroll 2
  for (int i4 = 0; i4 < IN_N/4; ++i4) {
    float4 sv = arow[i4];
    float svx[4];
    svx[0] = sv.x; svx[1] = sv.y; svx[2] = sv.z; svx[3] = sv.w;
#pragma unroll
    for (int u = 0; u < 4; ++u) {
      const float s = svx[u];
      const float* wp = &wsh[WOFF + (i4*4 + u)*OUT_TOT + o0];
      if constexpr (OUT_PW == 1) {
        acc[0] = fmaf(s, wp[0], acc[0]);
      } else if constexpr (OUT_PW == 2) {
        float2 w = *reinterpret_cast<const float2*>(wp);
        acc[0] = fmaf(s, w.x, acc[0]);
        acc[1] = fmaf(s, w.y, acc[1]);
      } else {
#pragma unroll
        for (int q = 0; q < OUT_PW/4; ++q) {
          float4 w = reinterpret_cast<const float4*>(wp)[q];
          acc[q*4+0] = fmaf(s, w.x, acc[q*4+0]);
          acc[q*4+1] = fmaf(s, w.y, acc[q*4+1]);
          acc[q*4+2] = fmaf(s, w.z, acc[q*4+2]);
          acc[q*4+3] = fmaf(s, w.w, acc[q*4+3]);
        }
      }
    }
  }
  float* orow = &act[lrow*ASTRIDE + OUT_BASE + o0];
  if constexpr (OUT_PW == 1) {
    orow[0] = RELU ? fmaxf(acc[0], 0.f) : acc[0];
  } else if constexpr (OUT_PW == 2) {
    float2 v;
    v.x = RELU ? fmaxf(acc[0], 0.f) : acc[0];
    v.y = RELU ? fmaxf(acc[1], 0.f) : acc[1];
    *reinterpret_cast<float2*>(orow) = v;
  } else {
#pragma unroll
    for (int q = 0; q < OUT_PW/4; ++q) {
      float4 v;
      v.x = RELU ? fmaxf(acc[q*4+0], 0.f) : acc[q*4+0];
      v.y = RELU ? fmaxf(acc[q*4+1], 0.f) : acc[q*4+1];
      v.z = RELU ? fmaxf(acc[q*4+2], 0.f) : acc[q*4+2];
      v.w = RELU ? fmaxf(acc[q*4+3], 0.f) : acc[q*4+3];
      reinterpret_cast<float4*>(orow)[q] = v;
    }
  }
}

// ---- K1: autoencoder + z + loss partials + fused center partials ----
__global__ __launch_bounds__(256, 4) void k1_ae(
    const float* __restrict__ table,
    const float* __restrict__ w1, const float* __restrict__ b1,
    const float* __restrict__ w2, const float* __restrict__ b2,
    const float* __restrict__ mw, const float* __restrict__ mb,
    const float* __restrict__ dw1, const float* __restrict__ db1,
    const float* __restrict__ dw2, const float* __restrict__ db2,
    const int* __restrict__ labels,
    float* __restrict__ ws)
{
  const int tid  = threadIdx.x;
  const int lrow = tid & (RPB-1);
  const int fway = tid >> 4;
  const int blk  = blockIdx.x;           // 0..767
  const int b    = blk / 96;
  const int ch   = blk % 96;

  __shared__ float wsh[LTOT];
  __shared__ float act[RPB * ASTRIDE];
  __shared__ int   lbl[RPB];
  __shared__ float lred[4];

  {
    float4* d4 = reinterpret_cast<float4*>(wsh);
#define CPY(off, src, nf4) \
    { const float4* p = reinterpret_cast<const float4*>(src); \
      for (int t = tid; t < (nf4); t += 256) d4[(off)/4 + t] = p[t]; }
    CPY(LW1,  w1,  128) CPY(LB1,  b1,  8)  CPY(LW2,  w2,  512)
    CPY(LB2,  b2,  16)  CPY(LMW,  mw,  256) CPY(LMB,  mb,  4)
    CPY(LDW1, dw1, 128) CPY(LDB1, db1, 8)  CPY(LDW2, dw2, 128)
    CPY(LDB2, db2, 4)
#undef CPY
    if (tid < RPB) lbl[tid] = labels[ch * RPB + tid];
    if (tid < RPB*4) {
      const float4 v = reinterpret_cast<const float4*>(table)[blk*(RPB*4) + tid];
      reinterpret_cast<float4*>(act)[(tid >> 2)*(ASTRIDE/4) + (tid & 3)] = v;
    }
  }
  __syncthreads();

  layerw<AX,  16, AH1, 2, 32, LW1,  LB1,  true >(act, wsh, lrow, fway);
  __syncthreads();
  layerw<AH1, 32, AH2, 4, 64, LW2,  LB2,  true >(act, wsh, lrow, fway);
  __syncthreads();
  layerw<AH2, 64, AZ,  1, 16, LMW,  LMB,  false>(act, wsh, lrow, fway);
  __syncthreads();

  if (tid < RPB*4) {
    const float4 zv =
      reinterpret_cast<const float4*>(act)[(tid >> 2)*(ASTRIDE/4) + (AZ/4) + (tid & 3)];
    reinterpret_cast<float4*>(ws + WS_Z)[blk*(RPB*4) + tid] = zv;
  }

  layerw<AZ,  16, AR1, 2, 32, LDW1, LDB1, true >(act, wsh, lrow, fway);
  __syncthreads();
  layerw<AR1, 32, AREC,1, 16, LDW2, LDB2, true >(act, wsh, lrow, fway);
  __syncthreads();

  {
    const float d = act[lrow*ASTRIDE + AREC + fway] - act[lrow*ASTRIDE + AX + fway];
    float ls = d * d;
    for (int off = 32; off > 0; off >>= 1) ls += __shfl_down(ls, off);
    if ((tid & 63) == 0) lred[tid >> 6] = ls;
    __syncthreads();
    if (tid == 0) ws[WS_LOSSP + blk] = (lred[0] + lred[1]) + (lred[2] + lred[3]);
  }

  {
    float a0 = 0.f, a1 = 0.f;
    const int d0 = tid & 15, k0 = tid >> 4;
    const int k1c = k0 + 16;
#pragma unroll
    for (int rr = 0; rr < RPB; ++rr) {
      const int lb = lbl[rr];
      const float zv = act[rr*ASTRIDE + AZ + d0];
      a0 += (lb == k0)  ? zv : 0.f;
      a1 += (lb == k1c) ? zv : 0.f;
    }
    ws[WS_CPART + (b*96 + ch)*512 + tid]       = a0;
    ws[WS_CPART + (b*96 + ch)*512 + 256 + tid] = a1;
  }
}

// ---- KMID: counts + centers (direct 96-sum) + d2 + MM partials + loss ------
// 48 blocks: (batch b, 256-row slice ib).
__global__ __launch_bounds__(256) void kmid(const int* __restrict__ labels,
                                            float* __restrict__ ws,
                                            float* __restrict__ out)
{
  const int bi = blockIdx.x;             // 0..47
  const int b = bi / 6, ib = bi % 6;
  const int tid = threadIdx.x;

  __shared__ int   cnt[KCLS];
  __shared__ int   lbls[256];
  __shared__ float cent[512];
  __shared__ float rmn[256], rmx[256];

  if (tid < KCLS) cnt[tid] = 0;
  __syncthreads();
#pragma unroll
  for (int c = 0; c < 6; ++c) {
    const int lb = labels[c*256 + tid];
    if (c == ib) lbls[tid] = lb;
    atomicAdd(&cnt[lb], 1);
  }

  // centers: 2 elems/thread, direct 96-chunk sum (coalesced, unroll-8 ILP)
  float s1 = 0.f, s2 = 0.f;
  {
    const float* cp = ws + WS_CPART + (b*96)*512;
#pragma unroll 8
    for (int c = 0; c < 96; ++c) {
      s1 += cp[c*512 + tid];
      s2 += cp[c*512 + 256 + tid];
    }
  }
  __syncthreads();
  {
    int cn1 = cnt[tid >> 4];         cn1 = cn1 > 1 ? cn1 : 1;
    int cn2 = cnt[(tid + 256) >> 4]; cn2 = cn2 > 1 ? cn2 : 1;
    cent[tid]       = s1 / (float)cn1;
    cent[tid + 256] = s2 / (float)cn2;
  }
  __syncthreads();

  // d2 for row r (1 row/thread) + block min/max partial
  const int r = ib*256 + tid;
  {
    const int lb = lbls[tid];
    const float4* zp = reinterpret_cast<const float4*>(ws + WS_Z + (b*ROWS + r)*16);
    const float4* cq = reinterpret_cast<const float4*>(&cent[lb*16]);
    float s = 0.f;
#pragma unroll
    for (int q = 0; q < 4; ++q) {
      float4 zv = zp[q], cv = cq[q];
      float d0 = zv.x - cv.x, d1 = zv.y - cv.y, d2_ = zv.z - cv.z, d3 = zv.w - cv.w;
      s += d0*d0 + d1*d1 + d2_*d2_ + d3*d3;
    }
    const float dv = s / 16.f;
    ws[WS_D2 + b*ROWS + r] = dv;
    rmn[tid] = dv; rmx[tid] = dv;
  }
  __syncthreads();
  for (int off = 128; off > 0; off >>= 1) {
    if (tid < off) {
      rmn[tid] = fminf(rmn[tid], rmn[tid + off]);
      rmx[tid] = fmaxf(rmx[tid], rmx[tid + off]);
    }
    __syncthreads();
  }
  if (tid == 0) {
    ws[WS_MM + bi*2]     = rmn[0];
    ws[WS_MM + bi*2 + 1] = rmx[0];
  }

  // loss reduce rides in block 0
  if (bi == 0) {
    __syncthreads();
    rmn[tid] = ws[WS_LOSSP + tid] + ws[WS_LOSSP + 256 + tid] + ws[WS_LOSSP + 512 + tid];
    __syncthreads();
    for (int off = 128; off > 0; off >>= 1) {
      if (tid < off) rmn[tid] += rmn[tid + off];
      __syncthreads();
    }
    if (tid == 0) out[3*NTOT] = rmn[0] / (float)ELEMS;
  }
}

// ---- KCOUNT: scores from d2 (LDS, deterministic) + BOTH stable rank
//      counts on scores (x is a positive affine map of s -> same order).
__global__ __launch_bounds__(256) void kcount(const int* __restrict__ labels,
                                              float* __restrict__ ws,
                                              float* __restrict__ out)
{
  const int bi = blockIdx.x;
  const int jb = bi & 3, rb = (bi >> 2) % 6, b = bi / 24;
  const int tid = threadIdx.x;

  alignas(16) __shared__ float s_l[ROWS];

  float mn = 3.0e38f, mx = -3.0e38f;
#pragma unroll
  for (int c = 0; c < 6; ++c) {
    mn = fminf(mn, ws[WS_MM + (b*6 + c)*2]);
    mx = fmaxf(mx, ws[WS_MM + (b*6 + c)*2 + 1]);
  }

#pragma unroll
  for (int c = 0; c < 6; ++c) {
    const int r = c*256 + tid;
    const float sc = (ws[WS_D2 + b*ROWS + r] - mn) / (mx - mn) + (float)labels[r];
    s_l[r] = sc;
    if (jb == 0 && c == rb) out[2*NTOT + b*ROWS + r] = sc;
  }
  __syncthreads();

  const int r0 = rb*256 + tid;
  const float si = s_l[r0];
  int asc = 0, dsc = 0;
  const int j0 = jb*384;
  const float4* s4p = reinterpret_cast<const float4*>(&s_l[j0]);
#pragma unroll 4
  for (int kk = 0; kk < 96; ++kk) {
    const float4 s4 = s4p[kk];
    const int j = j0 + kk*4;
    const bool t0 = (s4.x == si && j   < r0);
    const bool t1 = (s4.y == si && j+1 < r0);
    const bool t2 = (s4.z == si && j+2 < r0);
    const bool t3 = (s4.w == si && j+3 < r0);
    asc += (s4.x < si || t0) ? 1 : 0;
    asc += (s4.y < si || t1) ? 1 : 0;
    asc += (s4.z < si || t2) ? 1 : 0;
    asc += (s4.w < si || t3) ? 1 : 0;
    dsc += (s4.x > si || t0) ? 1 : 0;
    dsc += (s4.y > si || t1) ? 1 : 0;
    dsc += (s4.z > si || t2) ? 1 : 0;
    dsc += (s4.w > si || t3) ? 1 : 0;
  }
  int* wsi = reinterpret_cast<int*>(ws);
  wsi[WS_ASCP + jb*NTOT + b*ROWS + r0] = asc;
  wsi[WS_DSCP + jb*NTOT + b*ROWS + r0] = dsc;
}

// ------- K67 (1024 thr): finalize counts -> rank_idx; smn/smx; xs; scan -----
__global__ __launch_bounds__(1024) void k67(const int* __restrict__ bsp,
                                            float* __restrict__ ws,
                                            float* __restrict__ out)
{
  const int b = blockIdx.x, tid = threadIdx.x;
  const int lane = tid & 63, wav = tid >> 6;       // 16 waves
  __shared__ float xs_l[ROWS];
  __shared__ float wr1[16], wr2[16];
  __shared__ float wtot[16];
  const int* wsi = reinterpret_cast<const int*>(ws);
  int* wsw = reinterpret_cast<int*>(ws);
  const int BS = *bsp;

  // rows handled: r1 = tid; r2 = 1024 + tid (tid < 512)
  int dsc1 = 0, dsc2 = 0;
  float sv1, sv2 = 0.f;
  {
    const int idx = b*ROWS + tid;
    int asc = 0, dsc = 0;
#pragma unroll
    for (int jb = 0; jb < 4; ++jb) {
      asc += wsi[WS_ASCP + jb*NTOT + idx];
      dsc += wsi[WS_DSCP + jb*NTOT + idx];
    }
    out[NTOT + idx] = (float)(asc / BS + 1);
    wsw[WS_DESC + idx] = dsc;
    dsc1 = dsc;
    sv1 = out[2*NTOT + idx];
  }
  if (tid < 512) {
    const int idx = b*ROWS + 1024 + tid;
    int asc = 0, dsc = 0;
#pragma unroll
    for (int jb = 0; jb < 4; ++jb) {
      asc += wsi[WS_ASCP + jb*NTOT + idx];
      dsc += wsi[WS_DSCP + jb*NTOT + idx];
    }
    out[NTOT + idx] = (float)(asc / BS + 1);
    wsw[WS_DESC + idx] = dsc;
    dsc2 = dsc;
    sv2 = out[2*NTOT + idx];
  }

  // batch min/max of scores
  {
    float tmn = sv1, tmx = sv1;
    if (tid < 512) { tmn = fminf(tmn, sv2); tmx = fmaxf(tmx, sv2); }
    for (int off = 32; off > 0; off >>= 1) {
      tmn = fminf(tmn, __shfl_down(tmn, off));
      tmx = fmaxf(tmx, __shfl_down(tmx, off));
    }
    if (lane == 0) { wr1[wav] = tmn; wr2[wav] = tmx; }
  }
  __syncthreads();
  float smn = 3.0e38f, smx = -3.0e38f;
#pragma unroll
  for (int w = 0; w < 16; ++w) {
    smn = fminf(smn, wr1[w]); smx = fmaxf(smx, wr2[w]);
  }

  // xs scatter
  xs_l[dsc1] = (sv1 - smn) / (smx - smn) * 8.0f / 0.01f;
  if (tid < 512) xs_l[dsc2] = (sv2 - smn) / (smx - smn) * 8.0f / 0.01f;
  __syncthreads();

  // scan: threads 0..767, 2 elems each; wave shfl-scan + cross-wave LDS
  float y0 = 0.f, y1 = 0.f, own = 0.f;
  int base = 0;
  if (tid < 768) {
    base = tid * 2;
    y0 = (float)(ROWS - base)     - xs_l[base];
    y1 = (float)(ROWS - base - 1) - xs_l[base + 1];
    own = y0 + y1;
  }
  float v = own;
#pragma unroll
  for (int d = 1; d < 64; d <<= 1) {
    float o = __shfl_up(v, d);
    if (lane >= d) v += o;
  }
  if (lane == 63) wtot[wav] = v;
  __syncthreads();
  float wpre = 0.f;
  for (int w = 0; w < wav; ++w) wpre += wtot[w];
  float* S = ws + WS_S + b*SSTRIDE;
  if (tid < 768) {
    float run = wpre + (v - own);
    S[base] = run; run += y0;
    S[base + 1] = run; run += y1;
    if (tid == 767) S[ROWS] = run;
    ws[WS_XS + b*ROWS + base]     = xs_l[base];
    ws[WS_XS + b*ROWS + base + 1] = xs_l[base + 1];
  }
  // pad tail with BIG so k8a needs no masking (1536 entries)
  for (int p = tid; p < SSTRIDE - ROWS - 1; p += 1024) S[ROWS + 1 + p] = BIGF;
}

// ---------------- K8a: chunk-partial minima of segment averages --------------
__global__ __launch_bounds__(256) void k8a(float* __restrict__ ws)
{
  const int bi = blockIdx.x;
  const int c = bi & 7, ib = (bi >> 3) % 6, b = bi / 48;
  const int tid = threadIdx.x;
  __shared__ float Sseg[448];
  __shared__ float invl[192];
  const float* S = ws + WS_S + b*SSTRIDE;
  const int ibase = ib*256;
  const int segbase = ibase + c*192 + 1;
  Sseg[tid] = S[segbase + tid];
  if (tid < 192) {
    Sseg[256 + tid] = S[segbase + 256 + tid];
    invl[tid] = 1.0f / (float)(c*192 + tid + 1);
  }
  __syncthreads();
  const int i = ibase + tid;
  const float Si = S[i];
  float gm = 3.0e38f;
#pragma unroll 8
  for (int k = 0; k < 192; ++k)
    gm = fminf(gm, (Sseg[tid + k] - Si) * invl[k]);
  ws[WS_GPART + (b*8 + c)*ROWS + i] = gm;
}

// --------- K8b: reduce partials, prefix-max (isotonic), final ranks ----------
__global__ __launch_bounds__(768) void k8b(float* __restrict__ ws,
                                           float* __restrict__ out)
{
  const int b = blockIdx.x, tid = threadIdx.x;
  const int lane = tid & 63, wav = tid >> 6;
  __shared__ float g[ROWS];
  __shared__ float wtot[12];
  for (int t = tid; t < ROWS; t += 768) {
    float gm = 3.0e38f;
#pragma unroll
    for (int c = 0; c < 8; ++c)
      gm = fminf(gm, ws[WS_GPART + (b*8 + c)*ROWS + t]);
    g[t] = gm;
  }
  __syncthreads();
  const float a = g[2*tid], cc = g[2*tid + 1];
  float v = fmaxf(a, cc);
#pragma unroll
  for (int d = 1; d < 64; d <<= 1) {
    float o = __shfl_up(v, d);
    if (lane >= d) v = fmaxf(v, o);
  }
  if (lane == 63) wtot[wav] = v;
  __syncthreads();
  float wpre = -3.0e38f;
  for (int w = 0; w < wav; ++w) wpre = fmaxf(wpre, wtot[w]);
  float lex = __shfl_up(v, 1);
  if (lane == 0) lex = -3.0e38f;
  const float excl = fmaxf(wpre, lex);
  const float i0 = fmaxf(excl, a);
  const float i1 = fmaxf(i0, cc);
  g[2*tid] = i0; g[2*tid + 1] = i1;
  __syncthreads();
  const float* xs = ws + WS_XS + b*ROWS;
  const int* desc = reinterpret_cast<const int*>(ws) + WS_DESC + b*ROWS;
  for (int t = tid; t < ROWS; t += 768) {
    const int dr = desc[t];
    out[b*ROWS + t] = xs[dr] + g[dr];
  }
}

extern "C" void kernel_launch(void* const* d_in, const int* in_sizes, int n_in,
                              void* d_out, int out_size, void* d_ws, size_t ws_size,
                              hipStream_t stream) {
  const float* table = (const float*)d_in[0];
  const float* w1  = (const float*)d_in[1];
  const float* b1  = (const float*)d_in[2];
  const float* w2  = (const float*)d_in[3];
  const float* b2  = (const float*)d_in[4];
  const float* mw  = (const float*)d_in[5];
  const float* mb  = (const float*)d_in[6];
  const float* dw1 = (const float*)d_in[7];
  const float* db1 = (const float*)d_in[8];
  const float* dw2 = (const float*)d_in[9];
  const float* db2 = (const float*)d_in[10];
  const int* labels = (const int*)d_in[11];
  const int* bsp    = (const int*)d_in[12];
  float* out = (float*)d_out;
  float* ws  = (float*)d_ws;

  k1_ae<<<768, 256, 0, stream>>>(table, w1, b1, w2, b2, mw, mb, dw1, db1, dw2, db2, labels, ws);
  kmid<<<48, 256, 0, stream>>>(labels, ws, out);
  kcount<<<192, 256, 0, stream>>>(labels, ws, out);
  k67<<<8, 1024, 0, stream>>>(bsp, ws, out);
  k8a<<<384, 256, 0, stream>>>(ws);
  k8b<<<8, 768, 0, stream>>>(ws, out);
}

// Round 14
// 59.361 us; speedup vs baseline: 1.0957x; 1.0957x over previous
//
#include <hip/hip_runtime.h>

#define BATCH 8
#define ROWS 1536
#define KCLS 32
#define NTOT (BATCH*ROWS)        // 12288
#define ELEMS (NTOT*16)          // 196608
#define SSTRIDE 3073             // padded prefix-sum stride per batch
#define BIGF 1.0e30f

// workspace layout (float offsets)
enum : int {
  WS_Z     = 0,                          // [8][1536][16]
  WS_XS    = WS_Z + NTOT*16,             // [8][1536]
  WS_S     = WS_XS + NTOT,               // [8][3073] padded
  WS_DESC  = WS_S + BATCH*SSTRIDE,       // [8][1536] int
  WS_ASCP  = WS_DESC + NTOT,             // [4][12288] int
  WS_DSCP  = WS_ASCP + 4*NTOT,           // [4][12288] int
  WS_GPART = WS_DSCP + 4*NTOT,           // max([8][96][512] cpart, [8][8][1536] k8a)
  WS_LOSSP = WS_GPART + BATCH*96*512,    // [768]
  WS_D2    = WS_LOSSP + 768,             // [8][1536]
  WS_MM    = WS_D2 + NTOT,               // [48][2]
  WS_CPAR2 = WS_MM + 96,                 // [8][8][512] level-1 center partials
  WS_CNT   = WS_CPAR2 + BATCH*8*512,     // [32] int
};
#define WS_CPART WS_GPART   // disjoint lifetimes: cpart k1->kcen, gpart k8a->k8b

// LDS weight layout (float offsets)
#define LW1  0
#define LB1  512
#define LW2  544
#define LB2  2592
#define LMW  2656
#define LMB  3680
#define LDW1 3696
#define LDB1 4208
#define LDW2 4240
#define LDB2 4752
#define LTOT 4768

// activation features per row (float offsets, all multiples of 4)
#define AX   0
#define AH1  16
#define AH2  48
#define AZ   112
#define AR1  128
#define AREC 144
#define ASTRIDE 164   // row stride in floats; 164%32=4 -> 2-way max conflicts

#define RPB 16        // rows per block in k1

// One layer slice with 4 accumulator banks (one per float4 lane of the input)
// -> FMA dependency chains are IN_N/4 deep instead of IN_N.
template<int IN_BASE, int IN_N, int OUT_BASE, int OUT_PW, int OUT_TOT,
         int WOFF, int BOFF, bool RELU>
__device__ __forceinline__ void layerw(float* __restrict__ act,
                                       const float* __restrict__ wsh,
                                       int lrow, int fway)
{
  const int o0 = fway * OUT_PW;
  float a0[OUT_PW], a1[OUT_PW], a2[OUT_PW], a3[OUT_PW];
#pragma unroll
  for (int j = 0; j < OUT_PW; ++j) {
    a0[j] = wsh[BOFF + o0 + j];
    a1[j] = 0.f; a2[j] = 0.f; a3[j] = 0.f;
  }

  const float4* arow = reinterpret_cast<const float4*>(&act[lrow*ASTRIDE + IN_BASE]);
#pragma unroll
  for (int i4 = 0; i4 < IN_N/4; ++i4) {
    const float4 sv = arow[i4];
    const float* wp0 = &wsh[WOFF + (i4*4 + 0)*OUT_TOT + o0];
    const float* wp1 = &wsh[WOFF + (i4*4 + 1)*OUT_TOT + o0];
    const float* wp2 = &wsh[WOFF + (i4*4 + 2)*OUT_TOT + o0];
    const float* wp3 = &wsh[WOFF + (i4*4 + 3)*OUT_TOT + o0];
    if constexpr (OUT_PW == 1) {
      a0[0] = fmaf(sv.x, wp0[0], a0[0]);
      a1[0] = fmaf(sv.y, wp1[0], a1[0]);
      a2[0] = fmaf(sv.z, wp2[0], a2[0]);
      a3[0] = fmaf(sv.w, wp3[0], a3[0]);
    } else if constexpr (OUT_PW == 2) {
      const float2 w0 = *reinterpret_cast<const float2*>(wp0);
      const float2 w1 = *reinterpret_cast<const float2*>(wp1);
      const float2 w2 = *reinterpret_cast<const float2*>(wp2);
      const float2 w3 = *reinterpret_cast<const float2*>(wp3);
      a0[0] = fmaf(sv.x, w0.x, a0[0]); a0[1] = fmaf(sv.x, w0.y, a0[1]);
      a1[0] = fmaf(sv.y, w1.x, a1[0]); a1[1] = fmaf(sv.y, w1.y, a1[1]);
      a2[0] = fmaf(sv.z, w2.x, a2[0]); a2[1] = fmaf(sv.z, w2.y, a2[1]);
      a3[0] = fmaf(sv.w, w3.x, a3[0]); a3[1] = fmaf(sv.w, w3.y, a3[1]);
    } else {
#pragma unroll
      for (int q = 0; q < OUT_PW/4; ++q) {
        const float4 w0 = reinterpret_cast<const float4*>(wp0)[q];
        const float4 w1 = reinterpret_cast<const float4*>(wp1)[q];
        const float4 w2 = reinterpret_cast<const float4*>(wp2)[q];
        const float4 w3 = reinterpret_cast<const float4*>(wp3)[q];
        a0[q*4+0] = fmaf(sv.x, w0.x, a0[q*4+0]);
        a0[q*4+1] = fmaf(sv.x, w0.y, a0[q*4+1]);
        a0[q*4+2] = fmaf(sv.x, w0.z, a0[q*4+2]);
        a0[q*4+3] = fmaf(sv.x, w0.w, a0[q*4+3]);
        a1[q*4+0] = fmaf(sv.y, w1.x, a1[q*4+0]);
        a1[q*4+1] = fmaf(sv.y, w1.y, a1[q*4+1]);
        a1[q*4+2] = fmaf(sv.y, w1.z, a1[q*4+2]);
        a1[q*4+3] = fmaf(sv.y, w1.w, a1[q*4+3]);
        a2[q*4+0] = fmaf(sv.z, w2.x, a2[q*4+0]);
        a2[q*4+1] = fmaf(sv.z, w2.y, a2[q*4+1]);
        a2[q*4+2] = fmaf(sv.z, w2.z, a2[q*4+2]);
        a2[q*4+3] = fmaf(sv.z, w2.w, a2[q*4+3]);
        a3[q*4+0] = fmaf(sv.w, w3.x, a3[q*4+0]);
        a3[q*4+1] = fmaf(sv.w, w3.y, a3[q*4+1]);
        a3[q*4+2] = fmaf(sv.w, w3.z, a3[q*4+2]);
        a3[q*4+3] = fmaf(sv.w, w3.w, a3[q*4+3]);
      }
    }
  }

  float* orow = &act[lrow*ASTRIDE + OUT_BASE + o0];
  if constexpr (OUT_PW == 1) {
    float v = (a0[0] + a1[0]) + (a2[0] + a3[0]);
    orow[0] = RELU ? fmaxf(v, 0.f) : v;
  } else if constexpr (OUT_PW == 2) {
    float2 v;
    v.x = (a0[0] + a1[0]) + (a2[0] + a3[0]);
    v.y = (a0[1] + a1[1]) + (a2[1] + a3[1]);
    if (RELU) { v.x = fmaxf(v.x, 0.f); v.y = fmaxf(v.y, 0.f); }
    *reinterpret_cast<float2*>(orow) = v;
  } else {
#pragma unroll
    for (int q = 0; q < OUT_PW/4; ++q) {
      float4 v;
      v.x = (a0[q*4+0] + a1[q*4+0]) + (a2[q*4+0] + a3[q*4+0]);
      v.y = (a0[q*4+1] + a1[q*4+1]) + (a2[q*4+1] + a3[q*4+1]);
      v.z = (a0[q*4+2] + a1[q*4+2]) + (a2[q*4+2] + a3[q*4+2]);
      v.w = (a0[q*4+3] + a1[q*4+3]) + (a2[q*4+3] + a3[q*4+3]);
      if (RELU) {
        v.x = fmaxf(v.x, 0.f); v.y = fmaxf(v.y, 0.f);
        v.z = fmaxf(v.z, 0.f); v.w = fmaxf(v.w, 0.f);
      }
      reinterpret_cast<float4*>(orow)[q] = v;
    }
  }
}

// ---- K1: autoencoder + z + loss partials + fused center partials ----
__global__ __launch_bounds__(256, 4) void k1_ae(
    const float* __restrict__ table,
    const float* __restrict__ w1, const float* __restrict__ b1,
    const float* __restrict__ w2, const float* __restrict__ b2,
    const float* __restrict__ mw, const float* __restrict__ mb,
    const float* __restrict__ dw1, const float* __restrict__ db1,
    const float* __restrict__ dw2, const float* __restrict__ db2,
    const int* __restrict__ labels,
    float* __restrict__ ws)
{
  const int tid  = threadIdx.x;
  const int lrow = tid & (RPB-1);
  const int fway = tid >> 4;
  const int blk  = blockIdx.x;           // 0..767
  const int b    = blk / 96;
  const int ch   = blk % 96;

  __shared__ float wsh[LTOT];
  __shared__ float act[RPB * ASTRIDE];
  __shared__ int   lbl[RPB];
  __shared__ float lred[4];

  {
    float4* d4 = reinterpret_cast<float4*>(wsh);
#define CPY(off, src, nf4) \
    { const float4* p = reinterpret_cast<const float4*>(src); \
      for (int t = tid; t < (nf4); t += 256) d4[(off)/4 + t] = p[t]; }
    CPY(LW1,  w1,  128) CPY(LB1,  b1,  8)  CPY(LW2,  w2,  512)
    CPY(LB2,  b2,  16)  CPY(LMW,  mw,  256) CPY(LMB,  mb,  4)
    CPY(LDW1, dw1, 128) CPY(LDB1, db1, 8)  CPY(LDW2, dw2, 128)
    CPY(LDB2, db2, 4)
#undef CPY
    if (tid < RPB) lbl[tid] = labels[ch * RPB + tid];
    if (tid < RPB*4) {
      const float4 v = reinterpret_cast<const float4*>(table)[blk*(RPB*4) + tid];
      reinterpret_cast<float4*>(act)[(tid >> 2)*(ASTRIDE/4) + (tid & 3)] = v;
    }
  }
  __syncthreads();

  layerw<AX,  16, AH1, 2, 32, LW1,  LB1,  true >(act, wsh, lrow, fway);
  __syncthreads();
  layerw<AH1, 32, AH2, 4, 64, LW2,  LB2,  true >(act, wsh, lrow, fway);
  __syncthreads();
  layerw<AH2, 64, AZ,  1, 16, LMW,  LMB,  false>(act, wsh, lrow, fway);
  __syncthreads();

  if (tid < RPB*4) {
    const float4 zv =
      reinterpret_cast<const float4*>(act)[(tid >> 2)*(ASTRIDE/4) + (AZ/4) + (tid & 3)];
    reinterpret_cast<float4*>(ws + WS_Z)[blk*(RPB*4) + tid] = zv;
  }

  layerw<AZ,  16, AR1, 2, 32, LDW1, LDB1, true >(act, wsh, lrow, fway);
  __syncthreads();
  layerw<AR1, 32, AREC,1, 16, LDW2, LDB2, true >(act, wsh, lrow, fway);
  __syncthreads();

  {
    const float d = act[lrow*ASTRIDE + AREC + fway] - act[lrow*ASTRIDE + AX + fway];
    float ls = d * d;
    for (int off = 32; off > 0; off >>= 1) ls += __shfl_down(ls, off);
    if ((tid & 63) == 0) lred[tid >> 6] = ls;
    __syncthreads();
    if (tid == 0) ws[WS_LOSSP + blk] = (lred[0] + lred[1]) + (lred[2] + lred[3]);
  }

  {
    float a0 = 0.f, a1 = 0.f;
    const int d0 = tid & 15, k0 = tid >> 4;
    const int k1c = k0 + 16;
#pragma unroll
    for (int rr = 0; rr < RPB; ++rr) {
      const int lb = lbl[rr];
      const float zv = act[rr*ASTRIDE + AZ + d0];
      a0 += (lb == k0)  ? zv : 0.f;
      a1 += (lb == k1c) ? zv : 0.f;
    }
    ws[WS_CPART + (b*96 + ch)*512 + tid]       = a0;
    ws[WS_CPART + (b*96 + ch)*512 + 256 + tid] = a1;
  }
}

// ---- KCEN: level-1 center partials (64 blocks: batch x 8 groups of 12) ----
// block (0,0) also computes label counts (batch-invariant) and the loss.
__global__ __launch_bounds__(512) void kcen(const int* __restrict__ labels,
                                            float* __restrict__ ws,
                                            float* __restrict__ out)
{
  const int bi = blockIdx.x;             // 0..63
  const int b = bi >> 3, g = bi & 7;
  const int tid = threadIdx.x;           // 0..511

  const float* cp = ws + WS_CPART + (b*96 + g*12)*512 + tid;
  float s = 0.f;
#pragma unroll
  for (int c = 0; c < 12; ++c) s += cp[c*512];
  ws[WS_CPAR2 + (b*8 + g)*512 + tid] = s;

  if (bi == 0) {
    __shared__ int icnt[KCLS];
    __shared__ float red[512];
    if (tid < KCLS) icnt[tid] = 0;
    __syncthreads();
    atomicAdd(&icnt[labels[tid]], 1);
    atomicAdd(&icnt[labels[512 + tid]], 1);
    atomicAdd(&icnt[labels[1024 + tid]], 1);
    red[tid] = ws[WS_LOSSP + tid] + ((tid < 256) ? ws[WS_LOSSP + 512 + tid] : 0.f);
    __syncthreads();
    for (int off = 256; off > 0; off >>= 1) {
      if (tid < off) red[tid] += red[tid + off];
      __syncthreads();
    }
    if (tid == 0) out[3*NTOT] = red[0] / (float)ELEMS;
    if (tid < KCLS) reinterpret_cast<int*>(ws)[WS_CNT + tid] = icnt[tid];
  }
}

// ---- KD2: finalize centers (8 partials) + d2 + per-block minmax (48 blocks) -
__global__ __launch_bounds__(256) void kd2(const int* __restrict__ labels,
                                           float* __restrict__ ws)
{
  const int bi = blockIdx.x;             // 0..47
  const int b = bi / 6, ib = bi % 6;
  const int tid = threadIdx.x;

  __shared__ float cent[512];
  __shared__ float rmn[256], rmx[256];
  __shared__ int ci[KCLS];

  if (tid < KCLS) ci[tid] = reinterpret_cast<const int*>(ws)[WS_CNT + tid];
  float s1 = 0.f, s2 = 0.f;
#pragma unroll
  for (int g = 0; g < 8; ++g) {
    s1 += ws[WS_CPAR2 + (b*8 + g)*512 + tid];
    s2 += ws[WS_CPAR2 + (b*8 + g)*512 + 256 + tid];
  }
  __syncthreads();
  {
    int cn1 = ci[tid >> 4];         cn1 = cn1 > 1 ? cn1 : 1;
    int cn2 = ci[(tid + 256) >> 4]; cn2 = cn2 > 1 ? cn2 : 1;
    cent[tid]       = s1 / (float)cn1;
    cent[tid + 256] = s2 / (float)cn2;
  }
  __syncthreads();

  const int r = ib*256 + tid;
  const int lb = labels[r];
  const float4* zp = reinterpret_cast<const float4*>(ws + WS_Z + (b*ROWS + r)*16);
  const float4* cq = reinterpret_cast<const float4*>(&cent[lb*16]);
  float s = 0.f;
#pragma unroll
  for (int q = 0; q < 4; ++q) {
    float4 zv = zp[q], cv = cq[q];
    float d0 = zv.x - cv.x, d1 = zv.y - cv.y, d2_ = zv.z - cv.z, d3 = zv.w - cv.w;
    s += d0*d0 + d1*d1 + d2_*d2_ + d3*d3;
  }
  const float dv = s / 16.f;
  ws[WS_D2 + b*ROWS + r] = dv;
  rmn[tid] = dv; rmx[tid] = dv;
  __syncthreads();
  for (int off = 128; off > 0; off >>= 1) {
    if (tid < off) {
      rmn[tid] = fminf(rmn[tid], rmn[tid + off]);
      rmx[tid] = fmaxf(rmx[tid], rmx[tid + off]);
    }
    __syncthreads();
  }
  if (tid == 0) {
    ws[WS_MM + bi*2]     = rmn[0];
    ws[WS_MM + bi*2 + 1] = rmx[0];
  }
}

// ---- KCOUNT: scores from d2 (LDS, redundant-deterministic) + BOTH stable
//      rank counts on scores (x is a positive affine map of s -> same order).
__global__ __launch_bounds__(256) void kcount(const int* __restrict__ labels,
                                              float* __restrict__ ws,
                                              float* __restrict__ out)
{
  const int bi = blockIdx.x;
  const int jb = bi & 3, rb = (bi >> 2) % 6, b = bi / 24;
  const int tid = threadIdx.x;

  alignas(16) __shared__ float s_l[ROWS];

  float mn = 3.0e38f, mx = -3.0e38f;
#pragma unroll
  for (int c = 0; c < 6; ++c) {
    mn = fminf(mn, ws[WS_MM + (b*6 + c)*2]);
    mx = fmaxf(mx, ws[WS_MM + (b*6 + c)*2 + 1]);
  }

#pragma unroll
  for (int c = 0; c < 6; ++c) {
    const int r = c*256 + tid;
    const float sc = (ws[WS_D2 + b*ROWS + r] - mn) / (mx - mn) + (float)labels[r];
    s_l[r] = sc;
    if (jb == 0 && c == rb) out[2*NTOT + b*ROWS + r] = sc;
  }
  __syncthreads();

  const int r0 = rb*256 + tid;
  const float si = s_l[r0];
  int asc = 0, dsc = 0;
  const int j0 = jb*384;
  const float4* s4p = reinterpret_cast<const float4*>(&s_l[j0]);
#pragma unroll 4
  for (int kk = 0; kk < 96; ++kk) {
    const float4 s4 = s4p[kk];
    const int j = j0 + kk*4;
    const bool t0 = (s4.x == si && j   < r0);
    const bool t1 = (s4.y == si && j+1 < r0);
    const bool t2 = (s4.z == si && j+2 < r0);
    const bool t3 = (s4.w == si && j+3 < r0);
    asc += (s4.x < si || t0) ? 1 : 0;
    asc += (s4.y < si || t1) ? 1 : 0;
    asc += (s4.z < si || t2) ? 1 : 0;
    asc += (s4.w < si || t3) ? 1 : 0;
    dsc += (s4.x > si || t0) ? 1 : 0;
    dsc += (s4.y > si || t1) ? 1 : 0;
    dsc += (s4.z > si || t2) ? 1 : 0;
    dsc += (s4.w > si || t3) ? 1 : 0;
  }
  int* wsi = reinterpret_cast<int*>(ws);
  wsi[WS_ASCP + jb*NTOT + b*ROWS + r0] = asc;
  wsi[WS_DSCP + jb*NTOT + b*ROWS + r0] = dsc;
}

// ------- K67: finalize counts -> rank_idx; smn/smx; xs scatter; scan -> S ----
__global__ __launch_bounds__(256) void k67(const int* __restrict__ bsp,
                                           float* __restrict__ ws,
                                           float* __restrict__ out)
{
  const int b = blockIdx.x, tid = threadIdx.x;
  const int lane = tid & 63, wav = tid >> 6;
  __shared__ float xs_l[ROWS];
  __shared__ float rmn[256], rmx[256];
  __shared__ float wtot[4];
  const int* wsi = reinterpret_cast<const int*>(ws);
  int* wsw = reinterpret_cast<int*>(ws);
  const int BS = *bsp;

  int dscv[6];
  float sv[6];
  float tmn = 3.0e38f, tmx = -3.0e38f;
#pragma unroll
  for (int c = 0; c < 6; ++c) {
    const int r = c*256 + tid;
    const int idx = b*ROWS + r;
    int asc = 0, dsc = 0;
#pragma unroll
    for (int jb = 0; jb < 4; ++jb) {
      asc += wsi[WS_ASCP + jb*NTOT + idx];
      dsc += wsi[WS_DSCP + jb*NTOT + idx];
    }
    out[NTOT + idx] = (float)(asc / BS + 1);
    wsw[WS_DESC + idx] = dsc;
    dscv[c] = dsc;
    const float sc = out[2*NTOT + idx];
    sv[c] = sc;
    tmn = fminf(tmn, sc); tmx = fmaxf(tmx, sc);
  }
  rmn[tid] = tmn; rmx[tid] = tmx;
  __syncthreads();
  for (int off = 128; off > 0; off >>= 1) {
    if (tid < off) {
      rmn[tid] = fminf(rmn[tid], rmn[tid + off]);
      rmx[tid] = fmaxf(rmx[tid], rmx[tid + off]);
    }
    __syncthreads();
  }
  const float smn = rmn[0], smx = rmx[0];
  __syncthreads();

#pragma unroll
  for (int c = 0; c < 6; ++c) {
    const float scl = (sv[c] - smn) / (smx - smn) * 8.0f;
    xs_l[dscv[c]] = scl / 0.01f;
  }
  __syncthreads();

  const int base = tid * 6;
  float y[6], own = 0.f;
#pragma unroll
  for (int u = 0; u < 6; ++u) {
    ws[WS_XS + b*ROWS + base + u] = xs_l[base + u];
    y[u] = (float)(ROWS - (base + u)) - xs_l[base + u];
    own += y[u];
  }
  float v = own;
#pragma unroll
  for (int d = 1; d < 64; d <<= 1) {
    float o = __shfl_up(v, d);
    if (lane >= d) v += o;
  }
  if (lane == 63) wtot[wav] = v;
  __syncthreads();
  float wpre = 0.f;
  for (int w = 0; w < wav; ++w) wpre += wtot[w];
  float run = wpre + (v - own);
  float* S = ws + WS_S + b*SSTRIDE;
#pragma unroll
  for (int u = 0; u < 6; ++u) { S[base + u] = run; run += y[u]; }
  if (tid == 255) S[ROWS] = run;
#pragma unroll
  for (int u = 0; u < 6; ++u) S[ROWS + 1 + tid*6 + u] = BIGF;
}

// ---------------- K8a: chunk-partial minima of segment averages --------------
__global__ __launch_bounds__(256) void k8a(float* __restrict__ ws)
{
  const int bi = blockIdx.x;
  const int c = bi & 7, ib = (bi >> 3) % 6, b = bi / 48;
  const int tid = threadIdx.x;
  __shared__ float Sseg[448];
  __shared__ float invl[192];
  const float* S = ws + WS_S + b*SSTRIDE;
  const int ibase = ib*256;
  const int segbase = ibase + c*192 + 1;
  Sseg[tid] = S[segbase + tid];
  if (tid < 192) {
    Sseg[256 + tid] = S[segbase + 256 + tid];
    invl[tid] = 1.0f / (float)(c*192 + tid + 1);
  }
  __syncthreads();
  const int i = ibase + tid;
  const float Si = S[i];
  float gm = 3.0e38f;
#pragma unroll 8
  for (int k = 0; k < 192; ++k)
    gm = fminf(gm, (Sseg[tid + k] - Si) * invl[k]);
  ws[WS_GPART + (b*8 + c)*ROWS + i] = gm;
}

// --------- K8b: reduce partials, prefix-max (isotonic), final ranks ----------
__global__ __launch_bounds__(768) void k8b(float* __restrict__ ws,
                                           float* __restrict__ out)
{
  const int b = blockIdx.x, tid = threadIdx.x;
  const int lane = tid & 63, wav = tid >> 6;
  __shared__ float g[ROWS];
  __shared__ float wtot[12];
  for (int t = tid; t < ROWS; t += 768) {
    float gm = 3.0e38f;
#pragma unroll
    for (int c = 0; c < 8; ++c)
      gm = fminf(gm, ws[WS_GPART + (b*8 + c)*ROWS + t]);
    g[t] = gm;
  }
  __syncthreads();
  const float a = g[2*tid], cc = g[2*tid + 1];
  float v = fmaxf(a, cc);
#pragma unroll
  for (int d = 1; d < 64; d <<= 1) {
    float o = __shfl_up(v, d);
    if (lane >= d) v = fmaxf(v, o);
  }
  if (lane == 63) wtot[wav] = v;
  __syncthreads();
  float wpre = -3.0e38f;
  for (int w = 0; w < wav; ++w) wpre = fmaxf(wpre, wtot[w]);
  float lex = __shfl_up(v, 1);
  if (lane == 0) lex = -3.0e38f;
  const float excl = fmaxf(wpre, lex);
  const float i0 = fmaxf(excl, a);
  const float i1 = fmaxf(i0, cc);
  g[2*tid] = i0; g[2*tid + 1] = i1;
  __syncthreads();
  const float* xs = ws + WS_XS + b*ROWS;
  const int* desc = reinterpret_cast<const int*>(ws) + WS_DESC + b*ROWS;
  for (int t = tid; t < ROWS; t += 768) {
    const int dr = desc[t];
    out[b*ROWS + t] = xs[dr] + g[dr];
  }
}

extern "C" void kernel_launch(void* const* d_in, const int* in_sizes, int n_in,
                              void* d_out, int out_size, void* d_ws, size_t ws_size,
                              hipStream_t stream) {
  const float* table = (const float*)d_in[0];
  const float* w1  = (const float*)d_in[1];
  const float* b1  = (const float*)d_in[2];
  const float* w2  = (const float*)d_in[3];
  const float* b2  = (const float*)d_in[4];
  const float* mw  = (const float*)d_in[5];
  const float* mb  = (const float*)d_in[6];
  const float* dw1 = (const float*)d_in[7];
  const float* db1 = (const float*)d_in[8];
  const float* dw2 = (const float*)d_in[9];
  const float* db2 = (const float*)d_in[10];
  const int* labels = (const int*)d_in[11];
  const int* bsp    = (const int*)d_in[12];
  float* out = (float*)d_out;
  float* ws  = (float*)d_ws;

  k1_ae<<<768, 256, 0, stream>>>(table, w1, b1, w2, b2, mw, mb, dw1, db1, dw2, db2, labels, ws);
  kcen<<<64, 512, 0, stream>>>(labels, ws, out);
  kd2<<<48, 256, 0, stream>>>(labels, ws);
  kcount<<<192, 256, 0, stream>>>(labels, ws, out);
  k67<<<8, 256, 0, stream>>>(bsp, ws, out);
  k8a<<<384, 256, 0, stream>>>(ws);
  k8b<<<8, 768, 0, stream>>>(ws, out);
}